// Round 1
// baseline (340.183 us; speedup 1.0000x reference)
//
#include <hip/hip_runtime.h>
#include <math.h>

#define K_EMB 512
#define DIM 64
#define NVEC 65536                      // 64*32*32
#define OUT_LOSS 0
#define OUT_Q 1
#define OUT_PERP (1 + NVEC * DIM)       // 4194305
#define OUT_IDX (1 + NVEC * DIM + 1)    // 4194306

// ws layout (bytes):
//   0    : float    csq[512]   (2048 B)
//   2048 : unsigned hist[512]  (2048 B)
//   4096 : double   sse        (8 B)

// numpy pairwise_sum replica for sum(v*v) over 64 elements:
// r[j] = v[j]*v[j] + v[j+8]*v[j+8] + ... (sequential chain of 8), then
// ((r0+r1)+(r2+r3)) + ((r4+r5)+(r6+r7)). Products rounded BEFORE summing
// (no FMA contraction) — matches np.sum(flat*flat, axis=1).
__device__ __forceinline__ float np_pairwise8_sq(const float* v) {
    float r[8];
#pragma unroll
    for (int j = 0; j < 8; ++j) r[j] = __fmul_rn(v[j], v[j]);
#pragma unroll
    for (int i = 8; i < 64; i += 8) {
#pragma unroll
        for (int j = 0; j < 8; ++j) r[j] = __fadd_rn(r[j], __fmul_rn(v[i + j], v[i + j]));
    }
    return __fadd_rn(__fadd_rn(__fadd_rn(r[0], r[1]), __fadd_rn(r[2], r[3])),
                     __fadd_rn(__fadd_rn(r[4], r[5]), __fadd_rn(r[6], r[7])));
}

__global__ void vq_setup(const float* __restrict__ codebook, float* __restrict__ csq,
                         unsigned* __restrict__ hist, double* __restrict__ sse) {
    int k = threadIdx.x;  // 512 threads
    if (k == 0) *sse = 0.0;
    hist[k] = 0u;
    const float* c = codebook + k * DIM;
    float cv[64];
#pragma unroll
    for (int j = 0; j < 16; ++j) ((float4*)cv)[j] = ((const float4*)c)[j];
    csq[k] = np_pairwise8_sq(cv);
}

__launch_bounds__(256)
__global__ void vq_main(const float* __restrict__ inputs, const float* __restrict__ codebook,
                        const float* __restrict__ csq, unsigned* __restrict__ hist,
                        double* __restrict__ sse, float* __restrict__ out) {
    const int t = blockIdx.x * 256 + threadIdx.x;  // one thread per input vector
    const float* xp = inputs + (size_t)t * DIM;
    float x[64];
#pragma unroll
    for (int j = 0; j < 16; ++j) ((float4*)x)[j] = ((const float4*)xp)[j];

    const float A = np_pairwise8_sq(x);  // numpy-order ||x||^2 (the big constant)

    float best = 3.4e38f;
    int bestk = 0;
#pragma unroll 2
    for (int k = 0; k < K_EMB; ++k) {
        const float* c = codebook + (k << 6);  // wave-uniform address -> s_load
        float p[8] = {0.f, 0.f, 0.f, 0.f, 0.f, 0.f, 0.f, 0.f};
#pragma unroll
        for (int i = 0; i < 64; i += 8) {
#pragma unroll
            for (int j = 0; j < 8; ++j) p[j] = __builtin_fmaf(x[i + j], c[i + j], p[j]);
        }
        float dot = __fadd_rn(__fadd_rn(__fadd_rn(p[0], p[1]), __fadd_rn(p[2], p[3])),
                              __fadd_rn(__fadd_rn(p[4], p[5]), __fadd_rn(p[6], p[7])));
        // numpy: d2 = (A - 2*P) + csq, each op rounded in fp32
        float d2 = __fadd_rn(__fsub_rn(A, __fmul_rn(2.0f, dot)), csq[k]);
        if (d2 < best) { best = d2; bestk = k; }  // strict <: first-occurrence argmin
    }

    // epilogue: quantized output + index + histogram + SSE
    const float* cq = codebook + (bestk << 6);
    float q[64];
#pragma unroll
    for (int j = 0; j < 16; ++j) ((float4*)q)[j] = ((const float4*)cq)[j];

    float* oq = out + OUT_Q + (size_t)t * DIM;
#pragma unroll
    for (int j = 0; j < 16; ++j) ((float4*)oq)[j] = ((const float4*)q)[j];

    out[OUT_IDX + t] = (float)bestk;
    atomicAdd(&hist[bestk], 1u);

    float es = 0.f;
#pragma unroll
    for (int i = 0; i < 64; ++i) {
        float d = q[i] - x[i];
        es = __builtin_fmaf(d, d, es);
    }
    // wave reduce (64 lanes), then block reduce (4 waves), then one double atomic
#pragma unroll
    for (int off = 32; off > 0; off >>= 1) es += __shfl_down(es, off);
    __shared__ float wsum[4];
    const int lane = threadIdx.x & 63, wid = threadIdx.x >> 6;
    if (lane == 0) wsum[wid] = es;
    __syncthreads();
    if (threadIdx.x == 0)
        atomicAdd(sse, (double)(((wsum[0] + wsum[1]) + (wsum[2] + wsum[3]))));
}

__global__ void vq_final(const unsigned* __restrict__ hist, const double* __restrict__ sse,
                         float* __restrict__ out) {
    int k = threadIdx.x;  // 512 threads
    float p = (float)hist[k] / 65536.0f;
    float v = __fmul_rn(p, logf(__fadd_rn(p, 1e-10f)));
#pragma unroll
    for (int off = 32; off > 0; off >>= 1) v += __shfl_down(v, off);
    __shared__ float ws[8];
    const int lane = k & 63, wid = k >> 6;
    if (lane == 0) ws[wid] = v;
    __syncthreads();
    if (k == 0) {
        float S = 0.f;
#pragma unroll
        for (int i = 0; i < 8; ++i) S += ws[i];
        out[OUT_PERP] = expf(-S);
        float m = (float)(*sse / 4194304.0);  // exact /2^22
        out[OUT_LOSS] = __fadd_rn(m, __fmul_rn(0.25f, m));  // q_loss + 0.25*e_loss
    }
}

extern "C" void kernel_launch(void* const* d_in, const int* in_sizes, int n_in,
                              void* d_out, int out_size, void* d_ws, size_t ws_size,
                              hipStream_t stream) {
    const float* inputs   = (const float*)d_in[0];
    const float* codebook = (const float*)d_in[1];
    float* out = (float*)d_out;
    float*    csq  = (float*)d_ws;
    unsigned* hist = (unsigned*)((char*)d_ws + 2048);
    double*   sse  = (double*)((char*)d_ws + 4096);

    vq_setup<<<1, 512, 0, stream>>>(codebook, csq, hist, sse);
    vq_main<<<256, 256, 0, stream>>>(inputs, codebook, csq, hist, sse, out);
    vq_final<<<1, 512, 0, stream>>>(hist, sse, out);
}

// Round 2
// 208.052 us; speedup vs baseline: 1.6351x; 1.6351x over previous
//
#include <hip/hip_runtime.h>
#include <math.h>

#define K_EMB 512
#define DIM 64
#define NVEC 65536                      // 64*32*32
#define OUT_LOSS 0
#define OUT_Q 1
#define OUT_PERP (1 + NVEC * DIM)       // 4194305
#define OUT_IDX (1 + NVEC * DIM + 1)    // 4194306
#define NBLK 1024
#define VPB 64                          // vectors per block (4 threads each)

// ws layout (bytes): [0,8) double sse | [8,12) u32 done | [64,2112) u32 hist[512]

// numpy pairwise_sum replica for sum(v*v) over 64 elements (no FMA: products
// rounded before summing; 8 chains then pairwise combine) — matches np.sum.
__device__ __forceinline__ float np_pairwise8_sq(const float* v) {
    float r[8];
#pragma unroll
    for (int j = 0; j < 8; ++j) r[j] = __fmul_rn(v[j], v[j]);
#pragma unroll
    for (int i = 8; i < 64; i += 8) {
#pragma unroll
        for (int j = 0; j < 8; ++j) r[j] = __fadd_rn(r[j], __fmul_rn(v[i + j], v[i + j]));
    }
    return __fadd_rn(__fadd_rn(__fadd_rn(r[0], r[1]), __fadd_rn(r[2], r[3])),
                     __fadd_rn(__fadd_rn(r[4], r[5]), __fadd_rn(r[6], r[7])));
}

__launch_bounds__(256, 4)   // 128-VGPR budget: x[64] stays resident; 4 waves/SIMD is all we can fill
__global__ void vq_main(const float* __restrict__ inputs, const float* __restrict__ codebook,
                        unsigned* __restrict__ hist, double* __restrict__ sse,
                        unsigned* __restrict__ done, float* __restrict__ out) {
    __shared__ float s_csq[K_EMB];
    __shared__ float s_d2[256];
    __shared__ short s_bk[256];
    __shared__ float s_wsm[4];
    __shared__ int   s_last;

    const int tid = threadIdx.x;

    // per-block csq into LDS (numpy order, identical values to a global precompute)
    {
        const float* c = codebook + tid * 2 * DIM;
        float cv[64];
#pragma unroll
        for (int r = 0; r < 2; ++r) {
#pragma unroll
            for (int j = 0; j < 16; ++j) ((float4*)cv)[j] = ((const float4*)(c + r * DIM))[j];
            s_csq[tid * 2 + r] = np_pairwise8_sq(cv);
        }
    }
    __syncthreads();

    const int vec = blockIdx.x * VPB + (tid & 63);
    // wave id — force into SGPR so the codebook address is provably wave-uniform -> s_load
    const int quarter = __builtin_amdgcn_readfirstlane(tid >> 6);
    const int kbase = quarter << 7;   // 128 codewords per wave

    const float* xp = inputs + (size_t)vec * DIM;
    float x[64];
#pragma unroll
    for (int j = 0; j < 16; ++j) ((float4*)x)[j] = ((const float4*)xp)[j];

    const float A = np_pairwise8_sq(x);   // numpy-order ||x||^2

    float best = 3.4e38f;
    int bestk = kbase;
#pragma unroll 2
    for (int kk = 0; kk < 128; ++kk) {
        const int k = kbase + kk;
        const float* c = codebook + (k << 6);   // SGPR base + uniform k -> s_load
        float p[8] = {0.f, 0.f, 0.f, 0.f, 0.f, 0.f, 0.f, 0.f};
#pragma unroll
        for (int i = 0; i < 64; i += 8) {
#pragma unroll
            for (int j = 0; j < 8; ++j) p[j] = __builtin_fmaf(x[i + j], c[i + j], p[j]);
        }
        float dot = __fadd_rn(__fadd_rn(__fadd_rn(p[0], p[1]), __fadd_rn(p[2], p[3])),
                              __fadd_rn(__fadd_rn(p[4], p[5]), __fadd_rn(p[6], p[7])));
        float d2 = __fadd_rn(__fsub_rn(A, __fmul_rn(2.0f, dot)), s_csq[k]);
        if (d2 < best) { best = d2; bestk = k; }   // strict <: first occurrence in-range
    }
    s_d2[tid] = best;
    s_bk[tid] = (short)bestk;
    __syncthreads();

    // wave 0 owns the vectors: merge quarters (strict < + ascending q == global first-occurrence)
    if (tid < 64) {
        float bd = s_d2[tid];
        int   bk = s_bk[tid];
#pragma unroll
        for (int q = 1; q < 4; ++q) {
            float d = s_d2[tid + 64 * q];
            int   kq = s_bk[tid + 64 * q];
            if (d < bd) { bd = d; bk = kq; }
        }
        // epilogue: stream q in float4 chunks (keeps x + 4 q-floats live, not x + q[64])
        const float4* cb4 = (const float4*)(codebook + (bk << 6));
        float4* oq = (float4*)(out + OUT_Q + (size_t)vec * DIM);
        float es = 0.f;
#pragma unroll
        for (int j = 0; j < 16; ++j) {
            float4 qv = cb4[j];
            oq[j] = qv;
            float4 xv = ((float4*)x)[j];
            float d0 = qv.x - xv.x; es = __builtin_fmaf(d0, d0, es);
            float d1 = qv.y - xv.y; es = __builtin_fmaf(d1, d1, es);
            float d2v = qv.z - xv.z; es = __builtin_fmaf(d2v, d2v, es);
            float d3 = qv.w - xv.w; es = __builtin_fmaf(d3, d3, es);
        }
        out[OUT_IDX + vec] = (float)bk;
        atomicAdd(&hist[bk], 1u);
#pragma unroll
        for (int off = 32; off > 0; off >>= 1) es += __shfl_down(es, off);
        if (tid == 0) atomicAdd(sse, (double)es);
    }
    __syncthreads();
    if (tid == 0) {
        __threadfence();
        unsigned n = atomicAdd(done, 1u);
        s_last = (n == NBLK - 1) ? 1 : 0;
    }
    __syncthreads();

    if (s_last) {   // last-finishing block computes loss + perplexity
        __threadfence();
        float v = 0.f;
#pragma unroll
        for (int r = 0; r < 2; ++r) {
            int k = tid + 256 * r;
            unsigned cnt = atomicAdd(&hist[k], 0u);   // coherent read
            float pr = (float)cnt / 65536.0f;
            v = __fadd_rn(v, __fmul_rn(pr, logf(__fadd_rn(pr, 1e-10f))));
        }
#pragma unroll
        for (int off = 32; off > 0; off >>= 1) v += __shfl_down(v, off);
        if ((tid & 63) == 0) s_wsm[tid >> 6] = v;
        __syncthreads();
        if (tid == 0) {
            float S = __fadd_rn(__fadd_rn(s_wsm[0], s_wsm[1]), __fadd_rn(s_wsm[2], s_wsm[3]));
            out[OUT_PERP] = expf(-S);
            double sv = atomicAdd(sse, 0.0);          // coherent read
            float m = (float)(sv / 4194304.0);        // exact /2^22
            out[OUT_LOSS] = __fadd_rn(m, __fmul_rn(0.25f, m));
        }
    }
}

extern "C" void kernel_launch(void* const* d_in, const int* in_sizes, int n_in,
                              void* d_out, int out_size, void* d_ws, size_t ws_size,
                              hipStream_t stream) {
    const float* inputs   = (const float*)d_in[0];
    const float* codebook = (const float*)d_in[1];
    float* out = (float*)d_out;
    double*   sse  = (double*)d_ws;
    unsigned* done = (unsigned*)((char*)d_ws + 8);
    unsigned* hist = (unsigned*)((char*)d_ws + 64);

    hipMemsetAsync(d_ws, 0, 4096, stream);
    vq_main<<<NBLK, 256, 0, stream>>>(inputs, codebook, hist, sse, done, out);
}

// Round 3
// 207.446 us; speedup vs baseline: 1.6399x; 1.0029x over previous
//
#include <hip/hip_runtime.h>
#include <math.h>

#define K_EMB 512
#define DIM 64
#define NVEC 65536                      // 64*32*32
#define OUT_LOSS 0
#define OUT_Q 1
#define OUT_PERP (1 + NVEC * DIM)       // 4194305
#define OUT_IDX (1 + NVEC * DIM + 1)    // 4194306
#define NBLK 1024
#define VPB 64                          // vectors per block (4 threads each)

// ws layout (bytes): [0,8) double sse | [8,12) u32 done | [64,2112) u32 hist[512]

// numpy pairwise_sum replica for sum(v*v) over 64 elements (no FMA: products
// rounded before summing; 8 chains then pairwise combine) — matches np.sum.
__device__ __forceinline__ float np_pairwise8_sq(const float* v) {
    float r[8];
#pragma unroll
    for (int j = 0; j < 8; ++j) r[j] = __fmul_rn(v[j], v[j]);
#pragma unroll
    for (int i = 8; i < 64; i += 8) {
#pragma unroll
        for (int j = 0; j < 8; ++j) r[j] = __fadd_rn(r[j], __fmul_rn(v[i + j], v[i + j]));
    }
    return __fadd_rn(__fadd_rn(__fadd_rn(r[0], r[1]), __fadd_rn(r[2], r[3])),
                     __fadd_rn(__fadd_rn(r[4], r[5]), __fadd_rn(r[6], r[7])));
}

// waves_per_eu(4,4): cap the occupancy TARGET at 4 waves/EU (not just the
// guaranteed minimum) so the register allocator gets a 128-VGPR budget and
// keeps x[64] resident instead of re-streaming it from L1 every k-iteration.
__attribute__((amdgpu_waves_per_eu(4, 4)))
__launch_bounds__(256)
__global__ void vq_main(const float* __restrict__ inputs, const float* __restrict__ codebook,
                        unsigned* __restrict__ hist, double* __restrict__ sse,
                        unsigned* __restrict__ done, float* __restrict__ out) {
    __shared__ float s_csq[K_EMB];
    __shared__ float s_d2[256];
    __shared__ short s_bk[256];
    __shared__ float s_wsm[4];
    __shared__ int   s_last;

    const int tid = threadIdx.x;

    // per-block csq into LDS (numpy order, identical values to a global precompute)
    {
        const float* c = codebook + tid * 2 * DIM;
        float cv[64];
#pragma unroll
        for (int r = 0; r < 2; ++r) {
#pragma unroll
            for (int j = 0; j < 16; ++j) ((float4*)cv)[j] = ((const float4*)(c + r * DIM))[j];
            s_csq[tid * 2 + r] = np_pairwise8_sq(cv);
        }
    }
    __syncthreads();

    const int vec = blockIdx.x * VPB + (tid & 63);
    // wave id — force into SGPR so the codebook address is provably wave-uniform
    const int quarter = __builtin_amdgcn_readfirstlane(tid >> 6);
    const int kbase = quarter << 7;   // 128 codewords per wave

    const float* xp = inputs + (size_t)vec * DIM;
    float x[64];
#pragma unroll
    for (int j = 0; j < 16; ++j) ((float4*)x)[j] = ((const float4*)xp)[j];

    const float A = np_pairwise8_sq(x);   // numpy-order ||x||^2

    float best = 3.4e38f;
    int bestk = kbase;
#pragma unroll 2
    for (int kk = 0; kk < 128; ++kk) {
        const int k = kbase + kk;
        const float* c = codebook + (k << 6);   // wave-uniform address
        float p[8] = {0.f, 0.f, 0.f, 0.f, 0.f, 0.f, 0.f, 0.f};
#pragma unroll
        for (int i = 0; i < 64; i += 8) {
#pragma unroll
            for (int j = 0; j < 8; ++j) p[j] = __builtin_fmaf(x[i + j], c[i + j], p[j]);
        }
        float dot = __fadd_rn(__fadd_rn(__fadd_rn(p[0], p[1]), __fadd_rn(p[2], p[3])),
                              __fadd_rn(__fadd_rn(p[4], p[5]), __fadd_rn(p[6], p[7])));
        float d2 = __fadd_rn(__fsub_rn(A, __fmul_rn(2.0f, dot)), s_csq[k]);
        if (d2 < best) { best = d2; bestk = k; }   // strict <: first occurrence in-range
    }
    s_d2[tid] = best;
    s_bk[tid] = (short)bestk;
    __syncthreads();

    // wave 0 owns the vectors: merge quarters (strict < + ascending q == global first-occurrence)
    if (tid < 64) {
        float bd = s_d2[tid];
        int   bk = s_bk[tid];
#pragma unroll
        for (int q = 1; q < 4; ++q) {
            float d = s_d2[tid + 64 * q];
            int   kq = s_bk[tid + 64 * q];
            if (d < bd) { bd = d; bk = kq; }
        }
        // epilogue: stream q in float4 chunks (keeps x + 4 q-floats live, not x + q[64])
        const float4* cb4 = (const float4*)(codebook + (bk << 6));
        float4* oq = (float4*)(out + OUT_Q + (size_t)vec * DIM);
        float es = 0.f;
#pragma unroll
        for (int j = 0; j < 16; ++j) {
            float4 qv = cb4[j];
            oq[j] = qv;
            float4 xv = ((float4*)x)[j];
            float d0 = qv.x - xv.x; es = __builtin_fmaf(d0, d0, es);
            float d1 = qv.y - xv.y; es = __builtin_fmaf(d1, d1, es);
            float d2v = qv.z - xv.z; es = __builtin_fmaf(d2v, d2v, es);
            float d3 = qv.w - xv.w; es = __builtin_fmaf(d3, d3, es);
        }
        out[OUT_IDX + vec] = (float)bk;
        atomicAdd(&hist[bk], 1u);
#pragma unroll
        for (int off = 32; off > 0; off >>= 1) es += __shfl_down(es, off);
        if (tid == 0) atomicAdd(sse, (double)es);
    }
    __syncthreads();
    if (tid == 0) {
        __threadfence();
        unsigned n = atomicAdd(done, 1u);
        s_last = (n == NBLK - 1) ? 1 : 0;
    }
    __syncthreads();

    if (s_last) {   // last-finishing block computes loss + perplexity
        __threadfence();
        float v = 0.f;
#pragma unroll
        for (int r = 0; r < 2; ++r) {
            int k = tid + 256 * r;
            unsigned cnt = atomicAdd(&hist[k], 0u);   // coherent read
            float pr = (float)cnt / 65536.0f;
            v = __fadd_rn(v, __fmul_rn(pr, logf(__fadd_rn(pr, 1e-10f))));
        }
#pragma unroll
        for (int off = 32; off > 0; off >>= 1) v += __shfl_down(v, off);
        if ((tid & 63) == 0) s_wsm[tid >> 6] = v;
        __syncthreads();
        if (tid == 0) {
            float S = __fadd_rn(__fadd_rn(s_wsm[0], s_wsm[1]), __fadd_rn(s_wsm[2], s_wsm[3]));
            out[OUT_PERP] = expf(-S);
            double sv = atomicAdd(sse, 0.0);          // coherent read
            float m = (float)(sv / 4194304.0);        // exact /2^22
            out[OUT_LOSS] = __fadd_rn(m, __fmul_rn(0.25f, m));
        }
    }
}

extern "C" void kernel_launch(void* const* d_in, const int* in_sizes, int n_in,
                              void* d_out, int out_size, void* d_ws, size_t ws_size,
                              hipStream_t stream) {
    const float* inputs   = (const float*)d_in[0];
    const float* codebook = (const float*)d_in[1];
    float* out = (float*)d_out;
    double*   sse  = (double*)d_ws;
    unsigned* done = (unsigned*)((char*)d_ws + 8);
    unsigned* hist = (unsigned*)((char*)d_ws + 64);

    hipMemsetAsync(d_ws, 0, 4096, stream);
    vq_main<<<NBLK, 256, 0, stream>>>(inputs, codebook, hist, sse, done, out);
}